// Round 5
// baseline (214.618 us; speedup 1.0000x reference)
//
#include <hip/hip_runtime.h>
#include <math.h>

#define B_  2
#define Q_  2048
#define CQ_ 512
#define H_  8
#define D_  64
#define M_  (B_*Q_)   // 4096
#define L2E 1.44269504088896f

typedef __bf16 bf16;
typedef __bf16 bf16x4 __attribute__((ext_vector_type(4)));
typedef __bf16 bf16x8 __attribute__((ext_vector_type(8)));
typedef float  f32x4  __attribute__((ext_vector_type(4)));
typedef float  f32x16 __attribute__((ext_vector_type(16)));

// async global->LDS, 16 bytes per lane; lds dest = wave-uniform base + lane*16
__device__ __forceinline__ void gl_lds16(const bf16* g, bf16* l) {
    __builtin_amdgcn_global_load_lds(
        (const __attribute__((address_space(1))) unsigned int*)g,
        (__attribute__((address_space(3))) unsigned int*)l, 16, 0, 0);
}

// ---------------------------------------------------------------------------
// fp32 -> bf16 conversion: q_x -> qxb, w_qkv+w_g -> wcat (concat rows), w_o -> wob
// ---------------------------------------------------------------------------
#define S0 (4096*512)    // q_x
#define S1 (1536*512)    // w_qkv
#define S2 (512*512)     // w_g
#define S3 (512*512)     // w_o
__global__ __launch_bounds__(256)
void convert_kernel(const float* __restrict__ qx, const float* __restrict__ wqkv,
                    const float* __restrict__ wg, const float* __restrict__ wo,
                    bf16* __restrict__ qxb, bf16* __restrict__ wcat, bf16* __restrict__ wob)
{
    const long long t = (long long)blockIdx.x * 256 + threadIdx.x;
    const long long e = t * 8;
    const float* src; bf16* dst;
    if (e < S0)                { src = qx + e;                  dst = qxb + e; }
    else if (e < S0 + S1)      { src = wqkv + (e - S0);         dst = wcat + (e - S0); }
    else if (e < S0 + S1 + S2) { src = wg + (e - S0 - S1);      dst = wcat + S1 + (e - S0 - S1); }
    else                       { src = wo + (e - S0 - S1 - S2); dst = wob + (e - S0 - S1 - S2); }
    const float4 a = *(const float4*)(src);
    const float4 b = *(const float4*)(src + 4);
    bf16x8 v;
    v[0] = (bf16)a.x; v[1] = (bf16)a.y; v[2] = (bf16)a.z; v[3] = (bf16)a.w;
    v[4] = (bf16)b.x; v[5] = (bf16)b.y; v[6] = (bf16)b.z; v[7] = (bf16)b.w;
    *(bf16x8*)dst = v;
}

// ---------------------------------------------------------------------------
// bf16 MFMA GEMM: C[M,N] = A[M,512] * W[N,512]^T, K=512, BK=32.
// EPI 0: n<512 -> q (scaled by log2e/8, [B,H,Q,D]); <1024 -> k (32x32 A-frag
//        order); <1536 -> v (32x32 A-frag order, transposed);
//        else gate: sigmoid(c+b_g) -> gb bf16 [M,512]
// EPI 1: out[m*512+n] = c + b_o[n]  (fp32)
//
// K frag order per (b,h), key kk, dim d:
//   off = (kk>>6)*4096 + ((kk>>5)&1)*2048 + (d>>4)*512
//       + ((d>>3)&1)*256 + (kk&31)*8 + (d&7)
// V^T frag order per (b,h):
//   off = (kk>>6)*4096 + (d>>5)*2048 + ((kk&63)>>4)*512
//       + ((kk>>3)&1)*256 + (d&31)*8 + (kk&7)
// ---------------------------------------------------------------------------
template<int BM, int BN, int EPI>
__global__ __launch_bounds__(256)
void gemm_bf16(const bf16* __restrict__ A, const bf16* __restrict__ W,
               const float* __restrict__ bvec, float* __restrict__ fout,
               bf16* __restrict__ qb, bf16* __restrict__ kb, bf16* __restrict__ vb,
               bf16* __restrict__ gb)
{
    constexpr int MI = BM / 32, NJ = BN / 32;
    __shared__ __align__(16) bf16 As[BM * 32];
    __shared__ __align__(16) bf16 Bs[BN * 32];

    const int t = threadIdx.x;
    const int w = t >> 6, lane = t & 63;
    const int l15 = lane & 15, quad = lane >> 4;
    const int wm = w & 1, wn = w >> 1;
    const int bm = blockIdx.x * BM;
    const int bn = blockIdx.y * BN;

    f32x4 acc[MI][NJ] = {};

    const int rr = t >> 2;
    const int cc = (t & 3) * 8;

    for (int k0 = 0; k0 < 512; k0 += 32) {
        #pragma unroll
        for (int i = 0; i < BM / 64; ++i)
            gl_lds16(A + (size_t)(bm + i * 64 + rr) * 512 + k0 + cc,
                     As + (i * 64 + w * 16) * 32);
        #pragma unroll
        for (int i = 0; i < BN / 64; ++i)
            gl_lds16(W + (size_t)(bn + i * 64 + rr) * 512 + k0 + cc,
                     Bs + (i * 64 + w * 16) * 32);
        __asm__ volatile("s_waitcnt vmcnt(0)" ::: "memory");
        __syncthreads();

        bf16x8 af[MI], bfr[NJ];
        #pragma unroll
        for (int i = 0; i < MI; ++i)
            af[i] = *(const bf16x8*)(As + (wm * (BM / 2) + i * 16 + l15) * 32 + quad * 8);
        #pragma unroll
        for (int j = 0; j < NJ; ++j)
            bfr[j] = *(const bf16x8*)(Bs + (wn * (BN / 2) + j * 16 + l15) * 32 + quad * 8);
        #pragma unroll
        for (int i = 0; i < MI; ++i)
            #pragma unroll
            for (int j = 0; j < NJ; ++j)
                acc[i][j] = __builtin_amdgcn_mfma_f32_16x16x32_bf16(af[i], bfr[j], acc[i][j], 0, 0, 0);
        __syncthreads();
    }

    #pragma unroll
    for (int i = 0; i < MI; ++i) {
        #pragma unroll
        for (int r = 0; r < 4; ++r) {
            const int m = bm + wm * (BM / 2) + i * 16 + quad * 4 + r;
            const int b = m >> 11, qq = m & 2047;
            #pragma unroll
            for (int j = 0; j < NJ; ++j) {
                const int n = bn + wn * (BN / 2) + j * 16 + l15;
                const float cval = acc[i][j][r];
                if constexpr (EPI == 0) {
                    const int part = n >> 9;
                    const int h = (n >> 6) & 7, d = n & 63;
                    const size_t bhbase = (size_t)(b * H_ + h) * (Q_ * D_);
                    if (part == 0) {
                        qb[bhbase + (size_t)qq * D_ + d] = (bf16)(cval * (0.125f * L2E));
                    } else if (part == 1) {
                        kb[bhbase + (qq >> 6) * 4096 + ((qq >> 5) & 1) * 2048
                           + (d >> 4) * 512 + ((d >> 3) & 1) * 256
                           + (qq & 31) * 8 + (d & 7)] = (bf16)cval;
                    } else if (part == 2) {
                        vb[bhbase + (qq >> 6) * 4096 + (d >> 5) * 2048
                           + ((qq & 63) >> 4) * 512 + ((qq >> 3) & 1) * 256
                           + (d & 31) * 8 + (qq & 7)] = (bf16)cval;
                    } else {
                        const int gcol = n & 511;
                        const float x = cval + bvec[gcol];
                        gb[(size_t)m * 512 + gcol] = (bf16)(1.f / (1.f + __expf(-x)));
                    }
                } else {
                    fout[(size_t)m * 512 + n] = cval + bvec[n];
                }
            }
        }
    }
}

// ---------------------------------------------------------------------------
// MFMA flash attention, 32x32x16 shape, transposed dataflow (S^T, O^T).
// Block = 4 waves x 32 q-rows = 128 q-rows of one (b,h); grid (16 bh, 16).
// Lane's q-row = q0 + wv*32 + (lane&31)  (lanes l, l+32 share q, split d/keys).
// K/V staged to LDS in fragment order (conflict-free), double-buffered via
// global_load_lds; ONE barrier per 64-key step. Q lives in registers as the
// MFMA B-operand (zero LDS cost). Bias fp32, register-prefetched 1 step ahead.
// Softmax exp2-domain, per-lane row stats, 1 shuffle per reduction.
// ---------------------------------------------------------------------------
__global__ __launch_bounds__(256, 1)
void attn_kernel(const bf16* __restrict__ qb, const bf16* __restrict__ kf,
                 const bf16* __restrict__ vf, const float* __restrict__ bias,
                 const bf16* __restrict__ g, bf16* __restrict__ og)
{
    __shared__ __align__(16) bf16 Ks[2][4096];
    __shared__ __align__(16) bf16 Vs[2][4096];
    __shared__ __align__(16) bf16 Ps[4][32 * 72];   // per-wave P^T [q][key], pad 72

    const int tid  = threadIdx.x;
    const int wv   = tid >> 6, lane = tid & 63;
    const int l31  = lane & 31, b5 = lane >> 5;
    const int x    = blockIdx.x;
    const int bh   = ((x & 7) << 1) | (x >> 3);   // XCD x%8 gets same-b head pair
    const int b    = bh >> 3, h = bh & 7;
    const int qg   = blockIdx.y * 128 + wv * 32 + l31;   // this lane's q-row

    // Q as B-operand: B[k = b5*8+j within 16-chunk][n = l31]
    const bf16* qp = qb + ((size_t)bh * Q_ + qg) * D_;
    bf16x8 bq[4];
    #pragma unroll
    for (int c = 0; c < 4; ++c)
        bq[c] = *(const bf16x8*)(qp + c * 16 + b5 * 8);

    f32x16 acc[2] = {};                  // O^T: acc[dg], d = dg*32+(r&3)+8*(r>>2)+4*b5
    float m_run = -INFINITY, l_run = 0.f;

    const bf16*  kfb  = kf + (size_t)bh * (Q_ * D_);
    const bf16*  vfb  = vf + (size_t)bh * (Q_ * D_);
    const float* brow = bias + ((size_t)b * Q_ + qg) * Q_;

    f32x4 bcur[8], bnxt[8];              // [kg*4+g], component r&3; key=32kg+8g+4b5+(r&3)

    // ---- prologue: stage tile 0 (each wave: 2 K-glds + 2 V-glds), bias 0 ----
    #pragma unroll
    for (int p = 0; p < 2; ++p) {
        gl_lds16(kfb + (wv * 2 + p) * 512 + lane * 8, Ks[0] + (wv * 2 + p) * 512);
        gl_lds16(vfb + (wv * 2 + p) * 512 + lane * 8, Vs[0] + (wv * 2 + p) * 512);
    }
    #pragma unroll
    for (int i = 0; i < 8; ++i)
        bcur[i] = *(const f32x4*)(brow + (i >> 2) * 32 + (i & 3) * 8 + b5 * 4);
    __asm__ volatile("s_waitcnt vmcnt(0)" ::: "memory");
    __syncthreads();

    bf16* pw = Ps[wv] + l31 * 72;

    int cur = 0;
    #pragma unroll 1
    for (int t = 0; t < 32; ++t) {
        // async-stage next tile + prefetch next bias
        if (t < 31) {
            const size_t off = (size_t)(t + 1) * 4096;
            #pragma unroll
            for (int p = 0; p < 2; ++p) {
                gl_lds16(kfb + off + (wv * 2 + p) * 512 + lane * 8,
                         Ks[cur ^ 1] + (wv * 2 + p) * 512);
                gl_lds16(vfb + off + (wv * 2 + p) * 512 + lane * 8,
                         Vs[cur ^ 1] + (wv * 2 + p) * 512);
            }
            const int k0n = (t + 1) * 64;
            #pragma unroll
            for (int i = 0; i < 8; ++i)
                bnxt[i] = *(const f32x4*)(brow + k0n + (i >> 2) * 32 + (i & 3) * 8 + b5 * 4);
        }

        // ---- scores S^T: two 32x32 tiles (key-groups), chained over 4 d-chunks ----
        const bf16* Kc = Ks[cur];
        f32x16 sv[2] = {};
        #pragma unroll
        for (int kg = 0; kg < 2; ++kg)
            #pragma unroll
            for (int c = 0; c < 4; ++c) {
                const bf16x8 ak = *(const bf16x8*)(Kc + kg * 2048 + c * 512 + lane * 8);
                sv[kg] = __builtin_amdgcn_mfma_f32_32x32x16_bf16(ak, bq[c], sv[kg], 0, 0, 0);
            }

        // ---- bias (fma with log2e) + online softmax, exp2 domain ----
        float sc[2][16];
        #pragma unroll
        for (int kg = 0; kg < 2; ++kg)
            #pragma unroll
            for (int r = 0; r < 16; ++r)
                sc[kg][r] = fmaf(bcur[kg * 4 + (r >> 2)][r & 3], L2E, sv[kg][r]);

        float tmax = -INFINITY;
        #pragma unroll
        for (int kg = 0; kg < 2; ++kg)
            #pragma unroll
            for (int r = 0; r < 16; ++r)
                tmax = fmaxf(tmax, sc[kg][r]);
        tmax = fmaxf(tmax, __shfl_xor(tmax, 32, 64));

        const float mn = fmaxf(m_run, tmax);
        const float alpha = __builtin_amdgcn_exp2f(m_run - mn);
        m_run = mn;

        float rsum = 0.f;
        #pragma unroll
        for (int kg = 0; kg < 2; ++kg)
            #pragma unroll
            for (int r = 0; r < 16; ++r) {
                sc[kg][r] = __builtin_amdgcn_exp2f(sc[kg][r] - mn);
                rsum += sc[kg][r];
            }
        rsum += __shfl_xor(rsum, 32, 64);
        l_run = l_run * alpha + rsum;
        acc[0] *= alpha;
        acc[1] *= alpha;

        // ---- P^T -> per-wave LDS [q][key] (8x b64, 2-way max) ----
        #pragma unroll
        for (int kg = 0; kg < 2; ++kg)
            #pragma unroll
            for (int gi = 0; gi < 4; ++gi) {
                bf16x4 p4;
                p4[0] = (bf16)sc[kg][gi * 4 + 0];
                p4[1] = (bf16)sc[kg][gi * 4 + 1];
                p4[2] = (bf16)sc[kg][gi * 4 + 2];
                p4[3] = (bf16)sc[kg][gi * 4 + 3];
                *(bf16x4*)(pw + kg * 32 + gi * 8 + b5 * 4) = p4;
            }
        __asm__ volatile("s_waitcnt lgkmcnt(0)" ::: "memory");

        // ---- PV: O^T += V^T * P^T  (A=V^T frags, B=P^T frags) ----
        const bf16* Vc = Vs[cur];
        #pragma unroll
        for (int c4 = 0; c4 < 4; ++c4) {
            const bf16x8 bp = *(const bf16x8*)(pw + c4 * 16 + b5 * 8);
            #pragma unroll
            for (int dg = 0; dg < 2; ++dg) {
                const bf16x8 av = *(const bf16x8*)(Vc + dg * 2048 + c4 * 512 + lane * 8);
                acc[dg] = __builtin_amdgcn_mfma_f32_32x32x16_bf16(av, bp, acc[dg], 0, 0, 0);
            }
        }

        // ---- rotate bias regs; drain own glds; one barrier ----
        if (t < 31) {
            #pragma unroll
            for (int i = 0; i < 8; ++i) bcur[i] = bnxt[i];
        }
        __asm__ volatile("s_waitcnt vmcnt(0)" ::: "memory");
        __syncthreads();
        cur ^= 1;
    }

    // ---- normalize, gate, store bf16 (packed b64) ----
    const float inv = 1.f / l_run;
    const size_t obase = ((size_t)(b * Q_ + qg)) * 512 + h * 64;
    #pragma unroll
    for (int dg = 0; dg < 2; ++dg)
        #pragma unroll
        for (int gi = 0; gi < 4; ++gi) {
            const int d0 = dg * 32 + gi * 8 + b5 * 4;
            const bf16x4 gv = *(const bf16x4*)(g + obase + d0);
            bf16x4 ov;
            #pragma unroll
            for (int r = 0; r < 4; ++r)
                ov[r] = (bf16)(acc[dg][gi * 4 + r] * inv * (float)gv[r]);
            *(bf16x4*)(og + obase + d0) = ov;
        }
}

// ---------------------------------------------------------------------------
extern "C" void kernel_launch(void* const* d_in, const int* in_sizes, int n_in,
                              void* d_out, int out_size, void* d_ws, size_t ws_size,
                              hipStream_t stream)
{
    const float* q_x   = (const float*)d_in[0];
    const float* bias  = (const float*)d_in[2];
    const float* w_qkv = (const float*)d_in[3];
    const float* w_o   = (const float*)d_in[4];
    const float* b_o   = (const float*)d_in[5];
    const float* w_g   = (const float*)d_in[6];
    const float* b_g   = (const float*)d_in[7];
    float* out = (float*)d_out;

    char* ws = (char*)d_ws;
    bf16* qxb  = (bf16*)(ws);                    // 4 MB   [4096,512]
    bf16* wcat = (bf16*)(ws + (4u  << 20));      // 2 MB   [2048,512] = w_qkv ++ w_g
    bf16* wob  = (bf16*)(ws + (6u  << 20));      // 0.5 MB [512,512]
    bf16* qb   = (bf16*)(ws + (8u  << 20));      // 4 MB   [B,H,Q,D]
    bf16* kb   = (bf16*)(ws + (12u << 20));      // 4 MB   K fragment-ordered
    bf16* vb   = (bf16*)(ws + (16u << 20));      // 4 MB   V^T fragment-ordered
    bf16* gb   = (bf16*)(ws + (20u << 20));      // 4 MB   [4096,512]
    bf16* ogb  = (bf16*)(ws + (24u << 20));      // 4 MB   [4096,512]

    // 1) fp32 -> bf16 conversions
    convert_kernel<<<(S0 + S1 + S2 + S3) / (256 * 8), 256, 0, stream>>>(
        q_x, w_qkv, w_g, w_o, qxb, wcat, wob);
    // 2) fused QKV + gate projection (bf16 MFMA), N = 2048
    gemm_bf16<128, 128, 0><<<dim3(32, 16), 256, 0, stream>>>(
        qxb, wcat, b_g, nullptr, qb, kb, vb, gb);
    // 3) MFMA flash attention + gating
    attn_kernel<<<dim3(B_ * H_, Q_ / 128), 256, 0, stream>>>(qb, kb, vb, bias, gb, ogb);
    // 4) output projection + b_o
    gemm_bf16<64, 128, 1><<<dim3(64, 4), 256, 0, stream>>>(
        ogb, wob, b_o, out, nullptr, nullptr, nullptr, nullptr);
}

// Round 6
// 180.254 us; speedup vs baseline: 1.1906x; 1.1906x over previous
//
#include <hip/hip_runtime.h>
#include <math.h>

#define B_  2
#define Q_  2048
#define CQ_ 512
#define H_  8
#define D_  64
#define M_  (B_*Q_)   // 4096
#define L2E 1.44269504088896f

typedef __bf16 bf16;
typedef __bf16 bf16x4 __attribute__((ext_vector_type(4)));
typedef __bf16 bf16x8 __attribute__((ext_vector_type(8)));
typedef float  f32x4  __attribute__((ext_vector_type(4)));
typedef float  f32x16 __attribute__((ext_vector_type(16)));

// async global->LDS, 16 bytes per lane; lds dest = wave-uniform base + lane*16
__device__ __forceinline__ void gl_lds16(const bf16* g, bf16* l) {
    __builtin_amdgcn_global_load_lds(
        (const __attribute__((address_space(1))) unsigned int*)g,
        (__attribute__((address_space(3))) unsigned int*)l, 16, 0, 0);
}

// ---------------------------------------------------------------------------
// fp32 -> bf16 conversion
// ---------------------------------------------------------------------------
#define S0 (4096*512)    // q_x
#define S1 (1536*512)    // w_qkv
#define S2 (512*512)     // w_g
#define S3 (512*512)     // w_o
__global__ __launch_bounds__(256)
void convert_kernel(const float* __restrict__ qx, const float* __restrict__ wqkv,
                    const float* __restrict__ wg, const float* __restrict__ wo,
                    bf16* __restrict__ qxb, bf16* __restrict__ wcat, bf16* __restrict__ wob)
{
    const long long t = (long long)blockIdx.x * 256 + threadIdx.x;
    const long long e = t * 8;
    const float* src; bf16* dst;
    if (e < S0)                { src = qx + e;                  dst = qxb + e; }
    else if (e < S0 + S1)      { src = wqkv + (e - S0);         dst = wcat + (e - S0); }
    else if (e < S0 + S1 + S2) { src = wg + (e - S0 - S1);      dst = wcat + S1 + (e - S0 - S1); }
    else                       { src = wo + (e - S0 - S1 - S2); dst = wob + (e - S0 - S1 - S2); }
    const float4 a = *(const float4*)(src);
    const float4 b = *(const float4*)(src + 4);
    bf16x8 v;
    v[0] = (bf16)a.x; v[1] = (bf16)a.y; v[2] = (bf16)a.z; v[3] = (bf16)a.w;
    v[4] = (bf16)b.x; v[5] = (bf16)b.y; v[6] = (bf16)b.z; v[7] = (bf16)b.w;
    *(bf16x8*)dst = v;
}

// ---------------------------------------------------------------------------
// bf16 MFMA GEMM: C[M,N] = A[M,512] * W[N,512]^T, K=512, BK=32.
// For all parts except V we compute C^T (swapped mfma operands) so each lane
// holds 4 CONSECUTIVE n -> vector stores (b64/b128) instead of 64 scalars.
// EPI 0 (grid.y: 0-3 q, 4-7 k, 8-11 v, 12-15 gate), EPI 1: out = c + b_o.
// K frag order per (b,h), key kk, dim d:
//   off = (kk>>6)*4096 + ((kk>>5)&1)*2048 + (d>>4)*512 + ((d>>3)&1)*256
//       + (kk&31)*8 + (d&7)
// V^T frag order per (b,h):
//   off = (kk>>6)*4096 + (d>>5)*2048 + ((kk&63)>>4)*512 + ((kk>>3)&1)*256
//       + (d&31)*8 + (kk&7)
// ---------------------------------------------------------------------------
template<int BM, int BN, int EPI>
__global__ __launch_bounds__(256)
void gemm_bf16(const bf16* __restrict__ A, const bf16* __restrict__ W,
               const float* __restrict__ bvec, float* __restrict__ fout,
               bf16* __restrict__ qb, bf16* __restrict__ kb, bf16* __restrict__ vb,
               bf16* __restrict__ gb)
{
    constexpr int MI = BM / 32, NJ = BN / 32;
    __shared__ __align__(16) bf16 As[BM * 32];
    __shared__ __align__(16) bf16 Bs[BN * 32];

    const int t = threadIdx.x;
    const int w = t >> 6, lane = t & 63;
    const int l15 = lane & 15, quad = lane >> 4;
    const int wm = w & 1, wn = w >> 1;
    const int bm = blockIdx.x * BM;
    const int bn = blockIdx.y * BN;
    const bool swapped = (EPI == 1) || ((bn >> 9) != 2);

    f32x4 acc[MI][NJ] = {};

    const int rr = t >> 2;
    const int cc = (t & 3) * 8;

    for (int k0 = 0; k0 < 512; k0 += 32) {
        #pragma unroll
        for (int i = 0; i < BM / 64; ++i)
            gl_lds16(A + (size_t)(bm + i * 64 + rr) * 512 + k0 + cc,
                     As + (i * 64 + w * 16) * 32);
        #pragma unroll
        for (int i = 0; i < BN / 64; ++i)
            gl_lds16(W + (size_t)(bn + i * 64 + rr) * 512 + k0 + cc,
                     Bs + (i * 64 + w * 16) * 32);
        __asm__ volatile("s_waitcnt vmcnt(0)" ::: "memory");
        __syncthreads();

        bf16x8 af[MI], bfr[NJ];
        #pragma unroll
        for (int i = 0; i < MI; ++i)
            af[i] = *(const bf16x8*)(As + (wm * (BM / 2) + i * 16 + l15) * 32 + quad * 8);
        #pragma unroll
        for (int j = 0; j < NJ; ++j)
            bfr[j] = *(const bf16x8*)(Bs + (wn * (BN / 2) + j * 16 + l15) * 32 + quad * 8);
        if (swapped) {
            #pragma unroll
            for (int i = 0; i < MI; ++i)
                #pragma unroll
                for (int j = 0; j < NJ; ++j)
                    acc[i][j] = __builtin_amdgcn_mfma_f32_16x16x32_bf16(bfr[j], af[i], acc[i][j], 0, 0, 0);
        } else {
            #pragma unroll
            for (int i = 0; i < MI; ++i)
                #pragma unroll
                for (int j = 0; j < NJ; ++j)
                    acc[i][j] = __builtin_amdgcn_mfma_f32_16x16x32_bf16(af[i], bfr[j], acc[i][j], 0, 0, 0);
        }
        __syncthreads();
    }

    if (swapped) {
        #pragma unroll
        for (int i = 0; i < MI; ++i) {
            const int m = bm + wm * (BM / 2) + i * 16 + l15;
            const int b = m >> 11, qq = m & 2047;
            #pragma unroll
            for (int j = 0; j < NJ; ++j) {
                const int n0 = bn + wn * (BN / 2) + j * 16 + quad * 4;
                const f32x4 cv = acc[i][j];
                if constexpr (EPI == 1) {
                    float4 st;
                    st.x = cv[0] + bvec[n0 + 0];
                    st.y = cv[1] + bvec[n0 + 1];
                    st.z = cv[2] + bvec[n0 + 2];
                    st.w = cv[3] + bvec[n0 + 3];
                    *(float4*)(fout + (size_t)m * 512 + n0) = st;
                } else {
                    const int part = n0 >> 9;
                    if (part == 0) {
                        const int h = (n0 >> 6) & 7, d0 = n0 & 63;
                        bf16x4 q4;
                        #pragma unroll
                        for (int r = 0; r < 4; ++r) q4[r] = (bf16)(cv[r] * (0.125f * L2E));
                        *(bf16x4*)(qb + (size_t)(b * H_ + h) * (Q_ * D_) + (size_t)qq * 64 + d0) = q4;
                    } else if (part == 1) {
                        const int h = (n0 >> 6) & 7, d0 = n0 & 63;
                        const size_t off = (size_t)(b * H_ + h) * (Q_ * D_)
                            + (qq >> 6) * 4096 + ((qq >> 5) & 1) * 2048
                            + (d0 >> 4) * 512 + ((d0 >> 3) & 1) * 256
                            + (qq & 31) * 8 + (d0 & 7);
                        bf16x4 k4;
                        #pragma unroll
                        for (int r = 0; r < 4; ++r) k4[r] = (bf16)cv[r];
                        *(bf16x4*)(kb + off) = k4;
                    } else {
                        const int gcol = n0 & 511;
                        const float4 bv4 = *(const float4*)(bvec + gcol);
                        bf16x4 g4;
                        g4[0] = (bf16)(1.f / (1.f + __expf(-(cv[0] + bv4.x))));
                        g4[1] = (bf16)(1.f / (1.f + __expf(-(cv[1] + bv4.y))));
                        g4[2] = (bf16)(1.f / (1.f + __expf(-(cv[2] + bv4.z))));
                        g4[3] = (bf16)(1.f / (1.f + __expf(-(cv[3] + bv4.w))));
                        *(bf16x4*)(gb + (size_t)m * 512 + gcol) = g4;
                    }
                }
            }
        }
    } else {
        // V part, normal orientation: lane holds 4 consecutive qq for fixed d
        #pragma unroll
        for (int i = 0; i < MI; ++i) {
            const int m0 = bm + wm * (BM / 2) + i * 16 + quad * 4;
            const int b = m0 >> 11, qq0 = m0 & 2047;
            #pragma unroll
            for (int j = 0; j < NJ; ++j) {
                const int n = bn + wn * (BN / 2) + j * 16 + l15;
                const int h = (n >> 6) & 7, d = n & 63;
                const size_t off = (size_t)(b * H_ + h) * (Q_ * D_)
                    + (qq0 >> 6) * 4096 + (d >> 5) * 2048
                    + ((qq0 & 63) >> 4) * 512 + ((qq0 >> 3) & 1) * 256
                    + (d & 31) * 8 + (qq0 & 7);
                bf16x4 v4;
                #pragma unroll
                for (int r = 0; r < 4; ++r) v4[r] = (bf16)acc[i][j][r];
                *(bf16x4*)(vb + off) = v4;
            }
        }
    }
}

// ---------------------------------------------------------------------------
// Split-K MFMA flash attention (32x32x16, transposed dataflow S^T/O^T).
// Grid (16 bh, 16 qt, 2 ks) = 512 blocks -> 3 blocks/CU co-resident.
// Block = 4 waves x 32 q-rows = 128 q; key slab = ks*1024..+1024, 16 steps.
// K/V LDS-staged in fragment order via global_load_lds (conflict-free),
// double-buffered, one barrier/step. Partial out: normalized O (bf16) + m,l.
// ---------------------------------------------------------------------------
__global__ __launch_bounds__(256, 3)
void attn_part(const bf16* __restrict__ qb, const bf16* __restrict__ kf,
               const bf16* __restrict__ vf, const float* __restrict__ bias,
               bf16* __restrict__ po, float2* __restrict__ ml)
{
    __shared__ __align__(16) bf16 Ks[2][4096];
    __shared__ __align__(16) bf16 Vs[2][4096];
    __shared__ __align__(16) bf16 Ps[4][32 * 72];

    const int tid  = threadIdx.x;
    const int wv   = tid >> 6, lane = tid & 63;
    const int l31  = lane & 31, b5 = lane >> 5;
    const int x    = blockIdx.x;
    const int bh   = ((x & 7) << 1) | (x >> 3);   // XCD gets same-b head pair
    const int b    = bh >> 3;
    const int qg   = blockIdx.y * 128 + wv * 32 + l31;
    const int ks   = blockIdx.z;

    const bf16* qp = qb + ((size_t)bh * Q_ + qg) * D_;
    bf16x8 bq[4];
    #pragma unroll
    for (int c = 0; c < 4; ++c)
        bq[c] = *(const bf16x8*)(qp + c * 16 + b5 * 8);

    f32x16 acc[2] = {};
    float m_run = -INFINITY, l_run = 0.f;

    const bf16*  kfb  = kf + (size_t)bh * (Q_ * D_) + (size_t)ks * 16 * 4096;
    const bf16*  vfb  = vf + (size_t)bh * (Q_ * D_) + (size_t)ks * 16 * 4096;
    const float* brow = bias + ((size_t)b * Q_ + qg) * Q_ + ks * 1024;

    f32x4 bcur[8], bnxt[8];

    #pragma unroll
    for (int p = 0; p < 2; ++p) {
        gl_lds16(kfb + (wv * 2 + p) * 512 + lane * 8, Ks[0] + (wv * 2 + p) * 512);
        gl_lds16(vfb + (wv * 2 + p) * 512 + lane * 8, Vs[0] + (wv * 2 + p) * 512);
    }
    #pragma unroll
    for (int i = 0; i < 8; ++i)
        bcur[i] = *(const f32x4*)(brow + (i >> 2) * 32 + (i & 3) * 8 + b5 * 4);
    __asm__ volatile("s_waitcnt vmcnt(0)" ::: "memory");
    __syncthreads();

    bf16* pw = Ps[wv] + l31 * 72;

    int cur = 0;
    #pragma unroll 1
    for (int t = 0; t < 16; ++t) {
        if (t < 15) {
            const size_t off = (size_t)(t + 1) * 4096;
            #pragma unroll
            for (int p = 0; p < 2; ++p) {
                gl_lds16(kfb + off + (wv * 2 + p) * 512 + lane * 8,
                         Ks[cur ^ 1] + (wv * 2 + p) * 512);
                gl_lds16(vfb + off + (wv * 2 + p) * 512 + lane * 8,
                         Vs[cur ^ 1] + (wv * 2 + p) * 512);
            }
            const int k0n = (t + 1) * 64;
            #pragma unroll
            for (int i = 0; i < 8; ++i)
                bnxt[i] = *(const f32x4*)(brow + k0n + (i >> 2) * 32 + (i & 3) * 8 + b5 * 4);
        }

        const bf16* Kc = Ks[cur];
        f32x16 sv[2] = {};
        #pragma unroll
        for (int kg = 0; kg < 2; ++kg)
            #pragma unroll
            for (int c = 0; c < 4; ++c) {
                const bf16x8 ak = *(const bf16x8*)(Kc + kg * 2048 + c * 512 + lane * 8);
                sv[kg] = __builtin_amdgcn_mfma_f32_32x32x16_bf16(ak, bq[c], sv[kg], 0, 0, 0);
            }

        float sc[2][16];
        #pragma unroll
        for (int kg = 0; kg < 2; ++kg)
            #pragma unroll
            for (int r = 0; r < 16; ++r)
                sc[kg][r] = fmaf(bcur[kg * 4 + (r >> 2)][r & 3], L2E, sv[kg][r]);

        float tmax = -INFINITY;
        #pragma unroll
        for (int kg = 0; kg < 2; ++kg)
            #pragma unroll
            for (int r = 0; r < 16; ++r)
                tmax = fmaxf(tmax, sc[kg][r]);
        tmax = fmaxf(tmax, __shfl_xor(tmax, 32, 64));

        const float mn = fmaxf(m_run, tmax);
        const float alpha = __builtin_amdgcn_exp2f(m_run - mn);
        m_run = mn;

        float rsum = 0.f;
        #pragma unroll
        for (int kg = 0; kg < 2; ++kg)
            #pragma unroll
            for (int r = 0; r < 16; ++r) {
                sc[kg][r] = __builtin_amdgcn_exp2f(sc[kg][r] - mn);
                rsum += sc[kg][r];
            }
        rsum += __shfl_xor(rsum, 32, 64);
        l_run = l_run * alpha + rsum;
        acc[0] *= alpha;
        acc[1] *= alpha;

        #pragma unroll
        for (int kg = 0; kg < 2; ++kg)
            #pragma unroll
            for (int gi = 0; gi < 4; ++gi) {
                bf16x4 p4;
                p4[0] = (bf16)sc[kg][gi * 4 + 0];
                p4[1] = (bf16)sc[kg][gi * 4 + 1];
                p4[2] = (bf16)sc[kg][gi * 4 + 2];
                p4[3] = (bf16)sc[kg][gi * 4 + 3];
                *(bf16x4*)(pw + kg * 32 + gi * 8 + b5 * 4) = p4;
            }
        __asm__ volatile("s_waitcnt lgkmcnt(0)" ::: "memory");

        const bf16* Vc = Vs[cur];
        #pragma unroll
        for (int c4 = 0; c4 < 4; ++c4) {
            const bf16x8 bp = *(const bf16x8*)(pw + c4 * 16 + b5 * 8);
            #pragma unroll
            for (int dg = 0; dg < 2; ++dg) {
                const bf16x8 av = *(const bf16x8*)(Vc + dg * 2048 + c4 * 512 + lane * 8);
                acc[dg] = __builtin_amdgcn_mfma_f32_32x32x16_bf16(av, bp, acc[dg], 0, 0, 0);
            }
        }

        if (t < 15) {
            #pragma unroll
            for (int i = 0; i < 8; ++i) bcur[i] = bnxt[i];
        }
        __asm__ volatile("s_waitcnt vmcnt(0)" ::: "memory");
        __syncthreads();
        cur ^= 1;
    }

    // ---- partial epilogue: normalized O (bf16) + (m, l) ----
    const float inv = 1.f / l_run;
    const size_t pbase = ((size_t)(ks * 16 + bh) * Q_ + qg) * 64;
    #pragma unroll
    for (int dg = 0; dg < 2; ++dg)
        #pragma unroll
        for (int gi = 0; gi < 4; ++gi) {
            const int d0 = dg * 32 + gi * 8 + b5 * 4;
            bf16x4 ov;
            #pragma unroll
            for (int r = 0; r < 4; ++r)
                ov[r] = (bf16)(acc[dg][gi * 4 + r] * inv);
            *(bf16x4*)(po + pbase + d0) = ov;
        }
    if (b5 == 0)
        ml[(size_t)(ks * 16 + bh) * Q_ + qg] = make_float2(m_run, l_run);
}

// ---------------------------------------------------------------------------
// Merge 2 split-K partials, apply gate, write bf16 [M,512].
// ---------------------------------------------------------------------------
__global__ __launch_bounds__(256)
void merge_kernel(const bf16* __restrict__ po, const float2* __restrict__ ml,
                  const bf16* __restrict__ g, bf16* __restrict__ og)
{
    const int gid = blockIdx.x * 256 + threadIdx.x;
    const int row = gid >> 3;             // bh*2048 + qg
    const int d8  = (gid & 7) * 8;
    const int bh  = row >> 11, qg = row & 2047;
    const int b   = bh >> 3, h = bh & 7;

    const float2 ml0 = ml[row];
    const float2 ml1 = ml[16 * Q_ + row];
    const float  M   = fmaxf(ml0.x, ml1.x);
    const float  w0r = ml0.y * __builtin_amdgcn_exp2f(ml0.x - M);
    const float  w1r = ml1.y * __builtin_amdgcn_exp2f(ml1.x - M);
    const float  inv = 1.f / (w0r + w1r);
    const float  w0 = w0r * inv, w1 = w1r * inv;

    const bf16x8 o0 = *(const bf16x8*)(po + (size_t)row * 64 + d8);
    const bf16x8 o1 = *(const bf16x8*)(po + (size_t)16 * Q_ * 64 + (size_t)row * 64 + d8);
    const size_t obase = ((size_t)(b * Q_ + qg)) * 512 + h * 64 + d8;
    const bf16x8 gv = *(const bf16x8*)(g + obase);
    bf16x8 ov;
    #pragma unroll
    for (int r = 0; r < 8; ++r)
        ov[r] = (bf16)(((float)o0[r] * w0 + (float)o1[r] * w1) * (float)gv[r]);
    *(bf16x8*)(og + obase) = ov;
}

// ---------------------------------------------------------------------------
extern "C" void kernel_launch(void* const* d_in, const int* in_sizes, int n_in,
                              void* d_out, int out_size, void* d_ws, size_t ws_size,
                              hipStream_t stream)
{
    const float* q_x   = (const float*)d_in[0];
    const float* bias  = (const float*)d_in[2];
    const float* w_qkv = (const float*)d_in[3];
    const float* w_o   = (const float*)d_in[4];
    const float* b_o   = (const float*)d_in[5];
    const float* w_g   = (const float*)d_in[6];
    const float* b_g   = (const float*)d_in[7];
    float* out = (float*)d_out;

    char* ws = (char*)d_ws;
    bf16*   qxb  = (bf16*)(ws);                    // 4 MB  (dead after gemm)
    bf16*   wcat = (bf16*)(ws + (4u  << 20));      // 2 MB  (dead after gemm)
    bf16*   po   = (bf16*)(ws);                    // 8 MB  partials (overlays qxb/wcat)
    bf16*   qb   = (bf16*)(ws + (8u  << 20));      // 4 MB
    bf16*   kb   = (bf16*)(ws + (12u << 20));      // 4 MB  K frag-ordered
    bf16*   vb   = (bf16*)(ws + (16u << 20));      // 4 MB  V^T frag-ordered
    bf16*   gb   = (bf16*)(ws + (20u << 20));      // 4 MB  gate
    bf16*   ogb  = (bf16*)(ws + (24u << 20));      // 4 MB  gated O
    bf16*   wob  = (bf16*)(ws + (28u << 20));      // 0.5 MB
    float2* ml   = (float2*)(ws + (28u << 20) + (1u << 19));  // 0.5 MB

    // 1) fp32 -> bf16 conversions
    convert_kernel<<<(S0 + S1 + S2 + S3) / (256 * 8), 256, 0, stream>>>(
        q_x, w_qkv, w_g, w_o, qxb, wcat, wob);
    // 2) fused QKV + gate projection (bf16 MFMA, coalesced epilogue)
    gemm_bf16<128, 128, 0><<<dim3(32, 16), 256, 0, stream>>>(
        qxb, wcat, b_g, nullptr, qb, kb, vb, gb);
    // 3) split-K flash attention partials
    attn_part<<<dim3(B_ * H_, Q_ / 128, 2), 256, 0, stream>>>(qb, kb, vb, bias, po, ml);
    // 4) merge partials + gate
    merge_kernel<<<(16 * Q_ * 8) / 256, 256, 0, stream>>>(po, ml, gb, ogb);
    // 5) output projection + b_o
    gemm_bf16<64, 128, 1><<<dim3(64, 4), 256, 0, stream>>>(
        ogb, wob, b_o, out, nullptr, nullptr, nullptr, nullptr);
}